// Round 8
// baseline (218.598 us; speedup 1.0000x reference)
//
#include <hip/hip_runtime.h>

// GCN layer: out = relu( A0 @ (X W0) + A1 @ (X W1) )
//   X: [65536,128] fp32, W: [128,128] fp32, A*: COO (rows,cols,vals), E=1M each.
//
// Round 8: gather was throughput-bound in the L2-miss path (43% miss on H,
// flat vs MLP depth). Add a col-coarse pre-partition (pass 0) so the final
// per-row edge order is approximately col-ascending -> all gather blocks
// sweep H in near-lockstep -> live working set ~1-2 MB -> L2-resident.
// Pass 0 is co-launched with the MFMA GEMM (independent) in one kernel.
// Pipeline: w_swz -> memset -> hist_both -> scan_both -> [P0col || gemm]
//           -> partition_row2 -> bucket_sort -> gather_fused.

typedef unsigned int   uint;
typedef unsigned short ushort;
typedef unsigned char  uchar;
typedef float f32x4 __attribute__((ext_vector_type(4)));
typedef int   i32x4 __attribute__((ext_vector_type(4)));

constexpr int NB  = 256;   // coarse buckets (row>>8 / col>>8), BN=65536
constexpr int EPB = 8192;  // edges per partition/hist block

__device__ __forceinline__ ushort f2bf(float f) {      // fp32 -> bf16 RNE
    uint u = __float_as_uint(f);
    u += 0x7fffu + ((u >> 16) & 1u);
    return (ushort)(u >> 16);
}
__device__ __forceinline__ float bf2f(ushort h) {      // bf16 -> fp32 (exact)
    return __uint_as_float((uint)h << 16);
}

// MFMA D-write hazard fence (data-dependent s_nops).
#define ACC_FENCE(a) asm volatile("s_nop 7\n\ts_nop 7" : "+v"(a))

// ---- W pre-swizzle: B-fragment layout for mfma_f32_16x16x32_bf16 ---------
// frag (f,ct,kt): lane l, j=0..7 holds W[f][kt*32+(l>>4)*8+j][ct*16+(l&15)]
__global__ __launch_bounds__(64) void w_swz(const float* __restrict__ W0,
                                            const float* __restrict__ W1,
                                            uint4* __restrict__ Wswz) {
    const int bx = blockIdx.x;            // 0..63
    const int f  = bx >> 5;
    const int ct = (bx >> 2) & 7;
    const int kt = bx & 3;
    const int l  = threadIdx.x;           // 0..63
    const float* W = f ? W1 : W0;
    const int kbase = kt * 32 + (l >> 4) * 8;
    const int col   = ct * 16 + (l & 15);
    ushort h[8];
#pragma unroll
    for (int j = 0; j < 8; ++j)
        h[j] = f2bf(W[(kbase + j) * 128 + col]);
    uint4 o;
    o.x = (uint)h[0] | ((uint)h[1] << 16);
    o.y = (uint)h[2] | ((uint)h[3] << 16);
    o.z = (uint)h[4] | ((uint)h[5] << 16);
    o.w = (uint)h[6] | ((uint)h[7] << 16);
    Wswz[((f * 8 + ct) * 4 + kt) * 64 + l] = o;
}

// ---- hist_both: col-coarse AND row-coarse histograms in one read pass ----
__global__ __launch_bounds__(256) void hist_both(const int* __restrict__ r0,
                                                 const int* __restrict__ c0,
                                                 const int* __restrict__ r1,
                                                 const int* __restrict__ c1,
                                                 int* __restrict__ cnt_col,
                                                 int* __restrict__ cnt_row, int E) {
    __shared__ int hc[NB], hr[NB];
    const int f = blockIdx.y, t = threadIdx.x;
    const int* rows = f ? r1 : r0;
    const int* cols = f ? c1 : c0;
    hc[t] = 0; hr[t] = 0;
    __syncthreads();
    const int base = blockIdx.x * EPB;
    for (int k = 0; k < EPB / 256; ++k) {
        int e = base + k * 256 + t;
        if (e < E) {
            atomicAdd(&hc[cols[e] >> 8], 1);
            atomicAdd(&hr[rows[e] >> 8], 1);
        }
    }
    __syncthreads();
    if (hc[t]) atomicAdd(&cnt_col[f * NB + t], hc[t]);
    if (hr[t]) atomicAdd(&cnt_row[f * NB + t], hr[t]);
}

// ---- scan_both: 4 blocks = {f0,f1} x {col,row} ---------------------------
__global__ __launch_bounds__(256) void scan_both(const int* __restrict__ cnt_col,
                                                 const int* __restrict__ cnt_row,
                                                 int* __restrict__ ccur,
                                                 int* __restrict__ bbase,
                                                 int* __restrict__ bcur,
                                                 int* __restrict__ row_ptr,
                                                 int rp_stride, int BN, int E) {
    __shared__ int s[NB];
    const int bx = blockIdx.x, t = threadIdx.x;
    const int kind = bx >> 1, f = bx & 1;     // kind 0=col, 1=row
    const int* cnt = kind ? cnt_row : cnt_col;
    int v = cnt[f * NB + t];
    s[t] = v;
    __syncthreads();
    for (int off = 1; off < NB; off <<= 1) {
        int u = (t >= off) ? s[t - off] : 0;
        __syncthreads();
        s[t] += u;
        __syncthreads();
    }
    int base = s[t] - v;
    if (kind == 0) {
        ccur[f * NB + t] = base;
    } else {
        bbase[f * NB + t] = base;
        bcur [f * NB + t] = base;
        if (t == NB - 1) row_ptr[(size_t)f * rp_stride + BN] = E;
    }
}

// ---- fused: pass0 col-partition (blocks < 2*partb) || MFMA GEMM ----------
__global__ __launch_bounds__(256) void fused_p0_gemm(
        const float* __restrict__ X, const i32x4* __restrict__ Wswz,
        ushort* __restrict__ H, int BN,
        const int* __restrict__ r0, const int* __restrict__ c0,
        const float* __restrict__ v0,
        const int* __restrict__ r1, const int* __restrict__ c1,
        const float* __restrict__ v1,
        int* __restrict__ ccur, uint* __restrict__ colv,
        ushort* __restrict__ crow, int E, int partb) {
    __shared__ ushort xs_hi[64][136];         // gemm branch (34.8 KB)
    __shared__ ushort xs_lo[64][136];
    __shared__ int ph[NB], pcur[NB];          // P0 branch (2 KB)

    const int bx  = blockIdx.x;
    const int tid = threadIdx.x;

    if (bx < 2 * partb) {
        // ---- pass 0: partition by col>>8, chunked scatter ----
        const int f  = bx / partb;
        const int px = bx % partb;
        const int*   rows = f ? r1 : r0;
        const int*   cols = f ? c1 : c0;
        const float* vals = f ? v1 : v0;
        const int base = px * EPB;

        ph[tid] = 0;
        __syncthreads();
        for (int k = 0; k < EPB / 256; ++k) {
            int e = base + k * 256 + tid;
            if (e < E) atomicAdd(&ph[cols[e] >> 8], 1);
        }
        __syncthreads();
        pcur[tid] = atomicAdd(&ccur[f * NB + tid], ph[tid]);
        __syncthreads();

        uint*   yo = colv + (size_t)f * E;
        ushort* ro = crow + (size_t)f * E;
        for (int k = 0; k < EPB / 256; ++k) {
            int e = base + k * 256 + tid;
            if (e < E) {
                int c = cols[e];
                int pos = atomicAdd(&pcur[c >> 8], 1);
                yo[pos] = ((uint)c << 16) | (uint)f2bf(vals[e]);
                ro[pos] = (ushort)rows[e];
            }
        }
        return;
    }

    // ---- MFMA GEMM: H_f = X @ W_f (both filters), split-X hi/lo ----
    const int gx = bx - 2 * partb;
    const int l = tid & 63;
    const int w = tid >> 6;
    const long rbase = (long)gx * 64;

    const float4* Xv = reinterpret_cast<const float4*>(X + rbase * 128);
#pragma unroll
    for (int i = 0; i < 8; ++i) {
        int idx = i * 256 + tid;
        int row = idx >> 5, c4 = idx & 31;
        float4 v = Xv[idx];
        ushort4 hi, lo;
        hi.x = f2bf(v.x); lo.x = f2bf(v.x - bf2f(hi.x));
        hi.y = f2bf(v.y); lo.y = f2bf(v.y - bf2f(hi.y));
        hi.z = f2bf(v.z); lo.z = f2bf(v.z - bf2f(hi.z));
        hi.w = f2bf(v.w); lo.w = f2bf(v.w - bf2f(hi.w));
        *reinterpret_cast<ushort4*>(&xs_hi[row][c4 * 4]) = hi;
        *reinterpret_cast<ushort4*>(&xs_lo[row][c4 * 4]) = lo;
    }
    __syncthreads();

    i32x4 a_hi[4], a_lo[4];
    const int arow = w * 16 + (l & 15);
    const int kb = (l >> 4) * 8;
#pragma unroll
    for (int kt = 0; kt < 4; ++kt) {
        a_hi[kt] = *reinterpret_cast<const i32x4*>(&xs_hi[arow][kt * 32 + kb]);
        a_lo[kt] = *reinterpret_cast<const i32x4*>(&xs_lo[arow][kt * 32 + kb]);
    }

    f32x4 acc[2][8];
#pragma unroll
    for (int f = 0; f < 2; ++f)
#pragma unroll
        for (int ct = 0; ct < 8; ++ct)
            acc[f][ct] = (f32x4)0.0f;

#pragma unroll
    for (int ct = 0; ct < 8; ++ct)
#pragma unroll
        for (int f = 0; f < 2; ++f)
#pragma unroll
            for (int kt = 0; kt < 4; ++kt) {
                i32x4 b = Wswz[((f * 8 + ct) * 4 + kt) * 64 + l];
                asm volatile("v_mfma_f32_16x16x32_bf16 %0, %1, %2, %0"
                             : "+v"(acc[f][ct]) : "v"(a_hi[kt]), "v"(b));
                asm volatile("v_mfma_f32_16x16x32_bf16 %0, %1, %2, %0"
                             : "+v"(acc[f][ct]) : "v"(a_lo[kt]), "v"(b));
            }

    // D layout (HW-verified m89/m91): col = l&15, row = (l>>4)*4 + reg
#pragma unroll
    for (int ct = 0; ct < 8; ++ct)
#pragma unroll
        for (int f = 0; f < 2; ++f) {
            f32x4 a = acc[f][ct];
            ACC_FENCE(a);
            ushort* Hf = H + (size_t)f * BN * 128;
            size_t base = (size_t)(rbase + w * 16 + (l >> 4) * 4) * 128
                        + ct * 16 + (l & 15);
            Hf[base]       = f2bf(a.x);
            Hf[base + 128] = f2bf(a.y);
            Hf[base + 256] = f2bf(a.z);
            Hf[base + 384] = f2bf(a.w);
        }
}

// ---- pass 1: partition by row>>8, reading col-ordered packed stream ------
__global__ __launch_bounds__(256) void partition_row2(const uint* __restrict__ colv,
                                                      const ushort* __restrict__ crow,
                                                      int* __restrict__ bcur,
                                                      uint* __restrict__ cvy,
                                                      uchar* __restrict__ cvr, int E) {
    __shared__ int h[NB], cur[NB];
    const int f = blockIdx.y, t = threadIdx.x;
    const uint*   cvl = colv + (size_t)f * E;
    const ushort* cr  = crow + (size_t)f * E;
    const int base = blockIdx.x * EPB;

    h[t] = 0;
    __syncthreads();
    for (int k = 0; k < EPB / 256; ++k) {
        int e = base + k * 256 + t;
        if (e < E) atomicAdd(&h[cr[e] >> 8], 1);
    }
    __syncthreads();
    cur[t] = atomicAdd(&bcur[f * NB + t], h[t]);
    __syncthreads();

    uint*  yo = cvy + (size_t)f * E;
    uchar* ro = cvr + (size_t)f * E;
    for (int k = 0; k < EPB / 256; ++k) {
        int e = base + k * 256 + t;
        if (e < E) {
            ushort r = cr[e];
            int pos = atomicAdd(&cur[r >> 8], 1);
            yo[pos] = cvl[e];
            ro[pos] = (uchar)(r & 255);
        }
    }
}

// ---- pass 2: per-bucket sort by row&255, emits final cv + row_ptr --------
__global__ __launch_bounds__(256) void bucket_sort(const uint* __restrict__ cvy,
                                                   const uchar* __restrict__ cvr,
                                                   const int* __restrict__ bbase,
                                                   const int* __restrict__ bcur,
                                                   uint* __restrict__ cv,
                                                   int* __restrict__ row_ptr,
                                                   int rp_stride, int E) {
    __shared__ int h[NB];
    __shared__ int s[NB];
    __shared__ int curs[NB];
    const int f = blockIdx.y, b = blockIdx.x, t = threadIdx.x;
    const int start = bbase[f * NB + b];
    const int end   = bcur [f * NB + b];
    const uint*  yin = cvy + (size_t)f * E;
    const uchar* rin = cvr + (size_t)f * E;

    h[t] = 0;
    __syncthreads();
    for (int i = start + t; i < end; i += 256)
        atomicAdd(&h[rin[i]], 1);
    __syncthreads();

    int v = h[t];
    s[t] = v;
    __syncthreads();
    for (int off = 1; off < NB; off <<= 1) {
        int u = (t >= off) ? s[t - off] : 0;
        __syncthreads();
        s[t] += u;
        __syncthreads();
    }
    int rowbase = start + s[t] - v;
    row_ptr[(size_t)f * rp_stride + b * 256 + t] = rowbase;
    curs[t] = rowbase;
    __syncthreads();

    uint* outp = cv + (size_t)f * E;
    for (int i = start + t; i < end; i += 256) {
        int pos = atomicAdd(&curs[rin[i]], 1);
        outp[pos] = yin[i];
    }
}

// ---------------- round-7 fallback kernels --------------------------------
__global__ __launch_bounds__(256) void hist_coarse(const int* __restrict__ r0,
                                                   const int* __restrict__ r1,
                                                   int* __restrict__ cnt, int E) {
    __shared__ int h[NB];
    const int f = blockIdx.y, t = threadIdx.x;
    const int* rows = f ? r1 : r0;
    h[t] = 0;
    __syncthreads();
    const int base = blockIdx.x * EPB;
    for (int k = 0; k < EPB / 256; ++k) {
        int e = base + k * 256 + t;
        if (e < E) atomicAdd(&h[rows[e] >> 8], 1);
    }
    __syncthreads();
    if (h[t]) atomicAdd(&cnt[f * NB + t], h[t]);
}

__global__ __launch_bounds__(256) void scan_coarse(const int* __restrict__ cnt,
                                                   int* __restrict__ bbase,
                                                   int* __restrict__ bcur,
                                                   int* __restrict__ row_ptr,
                                                   int rp_stride, int BN, int E) {
    __shared__ int s[NB];
    const int f = blockIdx.x, t = threadIdx.x;
    int v = cnt[f * NB + t];
    s[t] = v;
    __syncthreads();
    for (int off = 1; off < NB; off <<= 1) {
        int u = (t >= off) ? s[t - off] : 0;
        __syncthreads();
        s[t] += u;
        __syncthreads();
    }
    int base = s[t] - v;
    bbase[f * NB + t] = base;
    bcur [f * NB + t] = base;
    if (t == NB - 1) row_ptr[(size_t)f * rp_stride + BN] = E;
}

__global__ __launch_bounds__(256) void partition(const int* __restrict__ r0,
                                                 const int* __restrict__ c0,
                                                 const float* __restrict__ v0,
                                                 const int* __restrict__ r1,
                                                 const int* __restrict__ c1,
                                                 const float* __restrict__ v1,
                                                 int* __restrict__ bcur,
                                                 uint* __restrict__ cvy,
                                                 uchar* __restrict__ cvr, int E) {
    __shared__ int h[NB];
    __shared__ int cur[NB];
    const int f = blockIdx.y, t = threadIdx.x;
    const int*   rows = f ? r1 : r0;
    const int*   cols = f ? c1 : c0;
    const float* vals = f ? v1 : v0;
    const int base = blockIdx.x * EPB;

    h[t] = 0;
    __syncthreads();
    for (int k = 0; k < EPB / 256; ++k) {
        int e = base + k * 256 + t;
        if (e < E) atomicAdd(&h[rows[e] >> 8], 1);
    }
    __syncthreads();
    cur[t] = atomicAdd(&bcur[f * NB + t], h[t]);
    __syncthreads();

    uint*  yout = cvy + (size_t)f * E;
    uchar* rout = cvr + (size_t)f * E;
    for (int k = 0; k < EPB / 256; ++k) {
        int e = base + k * 256 + t;
        if (e < E) {
            int r = rows[e];
            int pos = atomicAdd(&cur[r >> 8], 1);
            yout[pos] = ((uint)cols[e] << 16) | (uint)f2bf(vals[e]);
            rout[pos] = (uchar)(r & 255);
        }
    }
}

// Standalone MFMA GEMM for fallback paths.
__global__ __launch_bounds__(256) void gemm_mfma(const float* __restrict__ X,
                                                 const i32x4* __restrict__ Wswz,
                                                 ushort* __restrict__ H, int BN) {
    __shared__ ushort xs_hi[64][136];
    __shared__ ushort xs_lo[64][136];
    const int tid = threadIdx.x;
    const int l = tid & 63;
    const int w = tid >> 6;
    const long rbase = (long)blockIdx.x * 64;

    const float4* Xv = reinterpret_cast<const float4*>(X + rbase * 128);
#pragma unroll
    for (int i = 0; i < 8; ++i) {
        int idx = i * 256 + tid;
        int row = idx >> 5, c4 = idx & 31;
        float4 v = Xv[idx];
        ushort4 hi, lo;
        hi.x = f2bf(v.x); lo.x = f2bf(v.x - bf2f(hi.x));
        hi.y = f2bf(v.y); lo.y = f2bf(v.y - bf2f(hi.y));
        hi.z = f2bf(v.z); lo.z = f2bf(v.z - bf2f(hi.z));
        hi.w = f2bf(v.w); lo.w = f2bf(v.w - bf2f(hi.w));
        *reinterpret_cast<ushort4*>(&xs_hi[row][c4 * 4]) = hi;
        *reinterpret_cast<ushort4*>(&xs_lo[row][c4 * 4]) = lo;
    }
    __syncthreads();

    i32x4 a_hi[4], a_lo[4];
    const int arow = w * 16 + (l & 15);
    const int kb = (l >> 4) * 8;
#pragma unroll
    for (int kt = 0; kt < 4; ++kt) {
        a_hi[kt] = *reinterpret_cast<const i32x4*>(&xs_hi[arow][kt * 32 + kb]);
        a_lo[kt] = *reinterpret_cast<const i32x4*>(&xs_lo[arow][kt * 32 + kb]);
    }

    f32x4 acc[2][8];
#pragma unroll
    for (int f = 0; f < 2; ++f)
#pragma unroll
        for (int ct = 0; ct < 8; ++ct)
            acc[f][ct] = (f32x4)0.0f;

#pragma unroll
    for (int ct = 0; ct < 8; ++ct)
#pragma unroll
        for (int f = 0; f < 2; ++f)
#pragma unroll
            for (int kt = 0; kt < 4; ++kt) {
                i32x4 b = Wswz[((f * 8 + ct) * 4 + kt) * 64 + l];
                asm volatile("v_mfma_f32_16x16x32_bf16 %0, %1, %2, %0"
                             : "+v"(acc[f][ct]) : "v"(a_hi[kt]), "v"(b));
                asm volatile("v_mfma_f32_16x16x32_bf16 %0, %1, %2, %0"
                             : "+v"(acc[f][ct]) : "v"(a_lo[kt]), "v"(b));
            }

#pragma unroll
    for (int ct = 0; ct < 8; ++ct)
#pragma unroll
        for (int f = 0; f < 2; ++f) {
            f32x4 a = acc[f][ct];
            ACC_FENCE(a);
            ushort* Hf = H + (size_t)f * BN * 128;
            size_t base = (size_t)(rbase + w * 16 + (l >> 4) * 4) * 128
                        + ct * 16 + (l & 15);
            Hf[base]       = f2bf(a.x);
            Hf[base + 128] = f2bf(a.y);
            Hf[base + 256] = f2bf(a.z);
            Hf[base + 384] = f2bf(a.w);
        }
}

// ---------------- flat fallback (round-5) ---------------------------------
__global__ __launch_bounds__(256) void hist2(const int* __restrict__ r0,
                                             const int* __restrict__ r1,
                                             int* __restrict__ cnt, int E, int BN) {
    int e = blockIdx.x * 256 + threadIdx.x;
    const int* rows = blockIdx.y ? r1 : r0;
    if (e < E) atomicAdd(&cnt[(size_t)blockIdx.y * BN + rows[e]], 1);
}

__global__ __launch_bounds__(256) void scan2(int* __restrict__ cnt,
                                             int* __restrict__ row_ptr,
                                             int n, int rp_stride) {
    __shared__ int ssum[256];
    int* counts = cnt + (size_t)blockIdx.x * n;
    int* rp     = row_ptr + (size_t)blockIdx.x * rp_stride;
    const int t = threadIdx.x;
    const int chunk = n / 256;
    const int base = t * chunk;
    const int4* c4 = reinterpret_cast<const int4*>(counts + base);
    int s = 0;
#pragma unroll 4
    for (int i = 0; i < chunk / 4; ++i) {
        int4 v = c4[i];
        s += v.x + v.y + v.z + v.w;
    }
    ssum[t] = s;
    __syncthreads();
    for (int off = 1; off < 256; off <<= 1) {
        int u = (t >= off) ? ssum[t - off] : 0;
        __syncthreads();
        ssum[t] += u;
        __syncthreads();
    }
    int run = ssum[t] - s;
    int4* rp4 = reinterpret_cast<int4*>(rp + base);
    int4* cu4 = reinterpret_cast<int4*>(counts + base);
#pragma unroll 4
    for (int i = 0; i < chunk / 4; ++i) {
        int4 v = c4[i];
        int4 p;
        p.x = run; run += v.x;
        p.y = run; run += v.y;
        p.z = run; run += v.z;
        p.w = run; run += v.w;
        rp4[i] = p;
        cu4[i] = p;
    }
    if (t == 255) rp[n] = run;
}

__global__ __launch_bounds__(256) void permute2(const int* __restrict__ r0,
                                                const int* __restrict__ c0,
                                                const float* __restrict__ v0,
                                                const int* __restrict__ r1,
                                                const int* __restrict__ c1,
                                                const float* __restrict__ v1,
                                                int* __restrict__ cursor,
                                                uint* __restrict__ cv, int E, int BN) {
    int f = blockIdx.y;
    const int*   rows = f ? r1 : r0;
    const int*   cols = f ? c1 : c0;
    const float* vals = f ? v1 : v0;
    int e = blockIdx.x * 256 + threadIdx.x;
    if (e < E) {
        int r = rows[e];
        int pos = atomicAdd(&cursor[(size_t)f * BN + r], 1);
        cv[(size_t)f * E + pos] = ((uint)cols[e] << 16) | (uint)f2bf(vals[e]);
    }
}

// ---------------- fused gather: out[r] = relu(sum_A0 + sum_A1) ------------
__device__ __forceinline__ void fma4(float4& a, float v, ushort4 h) {
    a.x = fmaf(v, bf2f(h.x), a.x);
    a.y = fmaf(v, bf2f(h.y), a.y);
    a.z = fmaf(v, bf2f(h.z), a.z);
    a.w = fmaf(v, bf2f(h.w), a.w);
}

__global__ __launch_bounds__(256) void gather_fused(const int* __restrict__ row_ptr,
                                                    int rp_stride,
                                                    const uint* __restrict__ cv, int E,
                                                    const ushort* __restrict__ H, int BN,
                                                    float* __restrict__ out) {
    const int half = threadIdx.x >> 5;
    const int sub  = threadIdx.x & 31;
    const int r = blockIdx.x * 8 + half;

    float4 a0 = make_float4(0.f, 0.f, 0.f, 0.f);
    float4 a1 = make_float4(0.f, 0.f, 0.f, 0.f);
    float4 a2 = make_float4(0.f, 0.f, 0.f, 0.f);
    float4 a3 = make_float4(0.f, 0.f, 0.f, 0.f);

#pragma unroll
    for (int f = 0; f < 2; ++f) {
        const int*    rp  = row_ptr + (size_t)f * rp_stride;
        const uint*   cvf = cv + (size_t)f * E;
        const ushort* Hf  = H + (size_t)f * BN * 128;
        int e = rp[r];
        const int t = rp[r + 1];
        for (; e + 7 < t; e += 8) {
            uint p0 = cvf[e],     p1 = cvf[e + 1], p2 = cvf[e + 2], p3 = cvf[e + 3];
            uint p4 = cvf[e + 4], p5 = cvf[e + 5], p6 = cvf[e + 6], p7 = cvf[e + 7];
            ushort4 h0 = reinterpret_cast<const ushort4*>(Hf + (size_t)(p0 >> 16) * 128)[sub];
            ushort4 h1 = reinterpret_cast<const ushort4*>(Hf + (size_t)(p1 >> 16) * 128)[sub];
            ushort4 h2 = reinterpret_cast<const ushort4*>(Hf + (size_t)(p2 >> 16) * 128)[sub];
            ushort4 h3 = reinterpret_cast<const ushort4*>(Hf + (size_t)(p3 >> 16) * 128)[sub];
            ushort4 h4 = reinterpret_cast<const ushort4*>(Hf + (size_t)(p4 >> 16) * 128)[sub];
            ushort4 h5 = reinterpret_cast<const ushort4*>(Hf + (size_t)(p5 >> 16) * 128)[sub];
            ushort4 h6 = reinterpret_cast<const ushort4*>(Hf + (size_t)(p6 >> 16) * 128)[sub];
            ushort4 h7 = reinterpret_cast<const ushort4*>(Hf + (size_t)(p7 >> 16) * 128)[sub];
            fma4(a0, __uint_as_float(p0 << 16), h0);
            fma4(a1, __uint_as_float(p1 << 16), h1);
            fma4(a2, __uint_as_float(p2 << 16), h2);
            fma4(a3, __uint_as_float(p3 << 16), h3);
            fma4(a0, __uint_as_float(p4 << 16), h4);
            fma4(a1, __uint_as_float(p5 << 16), h5);
            fma4(a2, __uint_as_float(p6 << 16), h6);
            fma4(a3, __uint_as_float(p7 << 16), h7);
        }
        for (; e + 3 < t; e += 4) {
            uint p0 = cvf[e], p1 = cvf[e + 1], p2 = cvf[e + 2], p3 = cvf[e + 3];
            ushort4 h0 = reinterpret_cast<const ushort4*>(Hf + (size_t)(p0 >> 16) * 128)[sub];
            ushort4 h1 = reinterpret_cast<const ushort4*>(Hf + (size_t)(p1 >> 16) * 128)[sub];
            ushort4 h2 = reinterpret_cast<const ushort4*>(Hf + (size_t)(p2 >> 16) * 128)[sub];
            ushort4 h3 = reinterpret_cast<const ushort4*>(Hf + (size_t)(p3 >> 16) * 128)[sub];
            fma4(a0, __uint_as_float(p0 << 16), h0);
            fma4(a1, __uint_as_float(p1 << 16), h1);
            fma4(a2, __uint_as_float(p2 << 16), h2);
            fma4(a3, __uint_as_float(p3 << 16), h3);
        }
        for (; e < t; ++e) {
            uint p0 = cvf[e];
            ushort4 h0 = reinterpret_cast<const ushort4*>(Hf + (size_t)(p0 >> 16) * 128)[sub];
            fma4(a0, __uint_as_float(p0 << 16), h0);
        }
    }

    float4 o;
    o.x = fmaxf((a0.x + a1.x) + (a2.x + a3.x), 0.0f);
    o.y = fmaxf((a0.y + a1.y) + (a2.y + a3.y), 0.0f);
    o.z = fmaxf((a0.z + a1.z) + (a2.z + a3.z), 0.0f);
    o.w = fmaxf((a0.w + a1.w) + (a2.w + a3.w), 0.0f);
    reinterpret_cast<float4*>(out)[(size_t)r * 32 + sub] = o;
}

extern "C" void kernel_launch(void* const* d_in, const int* in_sizes, int n_in,
                              void* d_out, int out_size, void* d_ws, size_t ws_size,
                              hipStream_t stream) {
    const float* X     = (const float*)d_in[0];
    const float* W0    = (const float*)d_in[1];
    const float* W1    = (const float*)d_in[2];
    const int*   rows0 = (const int*)d_in[3];
    const int*   cols0 = (const int*)d_in[4];
    const float* vals0 = (const float*)d_in[5];
    const int*   rows1 = (const int*)d_in[6];
    const int*   cols1 = (const int*)d_in[7];
    const float* vals1 = (const float*)d_in[8];
    float* out = (float*)d_out;

    const int BN = in_sizes[0] / 128;               // 65536
    const int E  = in_sizes[3];                     // 1048576
    const int rp_stride = BN + 16;
    const int partb = (E + EPB - 1) / EPB;          // 128
    const int gath_blocks = BN / 8;                 // 8192

    char* ws = (char*)d_ws;
    size_t off = 0;
    auto alloc = [&](size_t bytes) {
        void* p = ws + off;
        off = (off + bytes + 255) & ~(size_t)255;
        return p;
    };
    // Common region
    ushort* H       = (ushort*)alloc((size_t)2 * BN * 128 * sizeof(ushort)); // 32 MiB
    int*    row_ptr = (int*)   alloc((size_t)2 * rp_stride * sizeof(int));
    uint4*  Wswz    = (uint4*) alloc((size_t)2 * 128 * 128 * sizeof(ushort)); // 128 KiB
    const size_t common = off;

    // New-path layout: colv(8M)+crow(4M) [colv reused as final cv] | cvy(8M)+cvr(2M) | counters
    uint*   colv = (uint*)  alloc((size_t)2 * E * sizeof(uint));
    ushort* crow = (ushort*)alloc((size_t)2 * E * sizeof(ushort));
    uint*   cvy  = (uint*)  alloc((size_t)2 * E * sizeof(uint));
    uchar*  cvr  = (uchar*) alloc((size_t)2 * E * sizeof(uchar));
    int*    cnts = (int*)   alloc((size_t)4 * NB * sizeof(int));  // [col f0,f1 | row f0,f1]
    int*    ccur = (int*)   alloc((size_t)2 * NB * sizeof(int));
    int*    bbase= (int*)   alloc((size_t)2 * NB * sizeof(int));
    int*    bcur = (int*)   alloc((size_t)2 * NB * sizeof(int));
    const size_t need_new = off;
    uint* cv_new = colv;                            // colv dead after pass 1

    w_swz<<<64, 64, 0, stream>>>(W0, W1, Wswz);

    if (ws_size >= need_new && BN == 65536) {
        int* cnt_col = cnts;
        int* cnt_row = cnts + 2 * NB;
        hipMemsetAsync(cnts, 0, (size_t)4 * NB * sizeof(int), stream);
        hist_both<<<dim3(partb, 2), 256, 0, stream>>>(rows0, cols0, rows1, cols1,
                                                      cnt_col, cnt_row, E);
        scan_both<<<4, 256, 0, stream>>>(cnt_col, cnt_row, ccur, bbase, bcur,
                                         row_ptr, rp_stride, BN, E);
        fused_p0_gemm<<<2 * partb + BN / 64, 256, 0, stream>>>(
            X, (const i32x4*)Wswz, H, BN,
            rows0, cols0, vals0, rows1, cols1, vals1,
            ccur, colv, crow, E, partb);
        partition_row2<<<dim3(partb, 2), 256, 0, stream>>>(colv, crow, bcur,
                                                           cvy, cvr, E);
        bucket_sort<<<dim3(NB, 2), 256, 0, stream>>>(cvy, cvr, bbase, bcur,
                                                     cv_new, row_ptr, rp_stride, E);
        gather_fused<<<gath_blocks, 256, 0, stream>>>(row_ptr, rp_stride, cv_new,
                                                      E, H, BN, out);
        return;
    }

    // ---- round-7 fallback: row-only two-level sort ----
    off = common;
    uint* cv = (uint*)alloc((size_t)2 * E * sizeof(uint));
    const size_t need_r7 = off + (size_t)2 * E * sizeof(uint)
                               + (size_t)2 * E * sizeof(uchar)
                               + 3 * (size_t)2 * NB * sizeof(int) + 1024;

    gemm_mfma<<<BN / 64, 256, 0, stream>>>(X, (const i32x4*)Wswz, H, BN);

    if (ws_size >= need_r7 && BN == 65536) {
        uint*  cvy2  = (uint*) alloc((size_t)2 * E * sizeof(uint));
        uchar* cvr2  = (uchar*)alloc((size_t)2 * E * sizeof(uchar));
        int*   cnt   = (int*)  alloc((size_t)2 * NB * sizeof(int));
        int*   bb2   = (int*)  alloc((size_t)2 * NB * sizeof(int));
        int*   bc2   = (int*)  alloc((size_t)2 * NB * sizeof(int));

        hipMemsetAsync(cnt, 0, (size_t)2 * NB * sizeof(int), stream);
        hist_coarse<<<dim3(partb, 2), 256, 0, stream>>>(rows0, rows1, cnt, E);
        scan_coarse<<<2, 256, 0, stream>>>(cnt, bb2, bc2, row_ptr, rp_stride, BN, E);
        partition<<<dim3(partb, 2), 256, 0, stream>>>(rows0, cols0, vals0,
                                                      rows1, cols1, vals1,
                                                      bc2, cvy2, cvr2, E);
        bucket_sort<<<dim3(NB, 2), 256, 0, stream>>>(cvy2, cvr2, bb2, bc2,
                                                     cv, row_ptr, rp_stride, E);
    } else {
        int* cursor = (int*)alloc((size_t)2 * BN * sizeof(int));
        const int edge_blocks = (E + 255) / 256;
        hipMemsetAsync(cursor, 0, (size_t)2 * BN * sizeof(int), stream);
        hist2<<<dim3(edge_blocks, 2), 256, 0, stream>>>(rows0, rows1, cursor, E, BN);
        scan2<<<2, 256, 0, stream>>>(cursor, row_ptr, BN, rp_stride);
        permute2<<<dim3(edge_blocks, 2), 256, 0, stream>>>(rows0, cols0, vals0,
                                                           rows1, cols1, vals1,
                                                           cursor, cv, E, BN);
    }

    gather_fused<<<gath_blocks, 256, 0, stream>>>(row_ptr, rp_stride, cv, E, H, BN, out);
}

// Round 9
// 166.945 us; speedup vs baseline: 1.3094x; 1.3094x over previous
//
#include <hip/hip_runtime.h>

// GCN layer: out = relu( A0 @ (X W0) + A1 @ (X W1) )
//   X: [65536,128] fp32, W: [128,128] fp32, A*: COO (rows,cols,vals), E=1M each.
//
// Round 9: revert r8's col-pre-sort + fusion (failed: row degree 16 -> no
// locality from intra-row col order; fused LDS killed occupancy). Gather's
// 232 MB FETCH == architectural L2-fill bound (8 XCDs x ~28 MB of the 32 MB
// all-to-all H working set) -- accept it. Instead remove sort-side cost:
// bucket_sort is fused INTO the gather (per-bucket LDS sort, no global cv
// round-trip, no row_ptr), NT hints keep out/edge streams from evicting H.
// Pipeline: w_swz -> gemm_mfma -> memset -> hist -> scan -> partition ->
//           sort_gather.

typedef unsigned int   uint;
typedef unsigned short ushort;
typedef unsigned char  uchar;
typedef float f32x4 __attribute__((ext_vector_type(4)));
typedef int   i32x4 __attribute__((ext_vector_type(4)));

constexpr int NB  = 256;   // coarse buckets: row >> 8 (BN = 65536)
constexpr int EPB = 8192;  // edges per partition/hist block
constexpr int CAP = 8192;  // per-filter LDS edge capacity (mean 4096 + 64 sigma)

__device__ __forceinline__ ushort f2bf(float f) {      // fp32 -> bf16 RNE
    uint u = __float_as_uint(f);
    u += 0x7fffu + ((u >> 16) & 1u);
    return (ushort)(u >> 16);
}
__device__ __forceinline__ float bf2f(ushort h) {      // bf16 -> fp32 (exact)
    return __uint_as_float((uint)h << 16);
}

// MFMA D-write hazard fence (data-dependent s_nops).
#define ACC_FENCE(a) asm volatile("s_nop 7\n\ts_nop 7" : "+v"(a))

// ---- W pre-swizzle: B-fragment layout for mfma_f32_16x16x32_bf16 ---------
// frag (f,ct,kt): lane l, j=0..7 holds W[f][kt*32+(l>>4)*8+j][ct*16+(l&15)]
__global__ __launch_bounds__(64) void w_swz(const float* __restrict__ W0,
                                            const float* __restrict__ W1,
                                            uint4* __restrict__ Wswz) {
    const int bx = blockIdx.x;            // 0..63
    const int f  = bx >> 5;
    const int ct = (bx >> 2) & 7;
    const int kt = bx & 3;
    const int l  = threadIdx.x;           // 0..63
    const float* W = f ? W1 : W0;
    const int kbase = kt * 32 + (l >> 4) * 8;
    const int col   = ct * 16 + (l & 15);
    ushort h[8];
#pragma unroll
    for (int j = 0; j < 8; ++j)
        h[j] = f2bf(W[(kbase + j) * 128 + col]);
    uint4 o;
    o.x = (uint)h[0] | ((uint)h[1] << 16);
    o.y = (uint)h[2] | ((uint)h[3] << 16);
    o.z = (uint)h[4] | ((uint)h[5] << 16);
    o.w = (uint)h[6] | ((uint)h[7] << 16);
    Wswz[((f * 8 + ct) * 4 + kt) * 64 + l] = o;
}

// ---- MFMA GEMM: H_f = X @ W_f (both filters), bf16 out, split-X accuracy --
__global__ __launch_bounds__(256) void gemm_mfma(const float* __restrict__ X,
                                                 const i32x4* __restrict__ Wswz,
                                                 ushort* __restrict__ H, int BN) {
    __shared__ ushort xs_hi[64][136];     // +8 pad
    __shared__ ushort xs_lo[64][136];
    const int tid = threadIdx.x;
    const int l = tid & 63;
    const int w = tid >> 6;
    const long rbase = (long)blockIdx.x * 64;

    const float4* Xv = reinterpret_cast<const float4*>(X + rbase * 128);
#pragma unroll
    for (int i = 0; i < 8; ++i) {
        int idx = i * 256 + tid;
        int row = idx >> 5, c4 = idx & 31;
        float4 v = Xv[idx];
        ushort4 hi, lo;
        hi.x = f2bf(v.x); lo.x = f2bf(v.x - bf2f(hi.x));
        hi.y = f2bf(v.y); lo.y = f2bf(v.y - bf2f(hi.y));
        hi.z = f2bf(v.z); lo.z = f2bf(v.z - bf2f(hi.z));
        hi.w = f2bf(v.w); lo.w = f2bf(v.w - bf2f(hi.w));
        *reinterpret_cast<ushort4*>(&xs_hi[row][c4 * 4]) = hi;
        *reinterpret_cast<ushort4*>(&xs_lo[row][c4 * 4]) = lo;
    }
    __syncthreads();

    i32x4 a_hi[4], a_lo[4];
    const int arow = w * 16 + (l & 15);
    const int kb = (l >> 4) * 8;
#pragma unroll
    for (int kt = 0; kt < 4; ++kt) {
        a_hi[kt] = *reinterpret_cast<const i32x4*>(&xs_hi[arow][kt * 32 + kb]);
        a_lo[kt] = *reinterpret_cast<const i32x4*>(&xs_lo[arow][kt * 32 + kb]);
    }

    f32x4 acc[2][8];
#pragma unroll
    for (int f = 0; f < 2; ++f)
#pragma unroll
        for (int ct = 0; ct < 8; ++ct)
            acc[f][ct] = (f32x4)0.0f;

#pragma unroll
    for (int ct = 0; ct < 8; ++ct)
#pragma unroll
        for (int f = 0; f < 2; ++f)
#pragma unroll
            for (int kt = 0; kt < 4; ++kt) {
                i32x4 b = Wswz[((f * 8 + ct) * 4 + kt) * 64 + l];
                asm volatile("v_mfma_f32_16x16x32_bf16 %0, %1, %2, %0"
                             : "+v"(acc[f][ct]) : "v"(a_hi[kt]), "v"(b));
                asm volatile("v_mfma_f32_16x16x32_bf16 %0, %1, %2, %0"
                             : "+v"(acc[f][ct]) : "v"(a_lo[kt]), "v"(b));
            }

    // D layout (HW-verified m89/m91): col = l&15, row = (l>>4)*4 + reg
#pragma unroll
    for (int ct = 0; ct < 8; ++ct)
#pragma unroll
        for (int f = 0; f < 2; ++f) {
            f32x4 a = acc[f][ct];
            ACC_FENCE(a);
            ushort* Hf = H + (size_t)f * BN * 128;
            size_t base = (size_t)(rbase + w * 16 + (l >> 4) * 4) * 128
                        + ct * 16 + (l & 15);
            Hf[base]       = f2bf(a.x);
            Hf[base + 128] = f2bf(a.y);
            Hf[base + 256] = f2bf(a.z);
            Hf[base + 384] = f2bf(a.w);
        }
}

// ---- hist: row-coarse histogram ------------------------------------------
__global__ __launch_bounds__(256) void hist_coarse(const int* __restrict__ r0,
                                                   const int* __restrict__ r1,
                                                   int* __restrict__ cnt, int E) {
    __shared__ int h[NB];
    const int f = blockIdx.y, t = threadIdx.x;
    const int* rows = f ? r1 : r0;
    h[t] = 0;
    __syncthreads();
    const int base = blockIdx.x * EPB;
    for (int k = 0; k < EPB / 256; ++k) {
        int e = base + k * 256 + t;
        if (e < E) atomicAdd(&h[rows[e] >> 8], 1);
    }
    __syncthreads();
    if (h[t]) atomicAdd(&cnt[f * NB + t], h[t]);
}

// ---- scan: exclusive scan of 256 bucket counts per filter ----------------
__global__ __launch_bounds__(256) void scan_coarse(const int* __restrict__ cnt,
                                                   int* __restrict__ bbase,
                                                   int* __restrict__ bcur) {
    __shared__ int s[NB];
    const int f = blockIdx.x, t = threadIdx.x;
    int v = cnt[f * NB + t];
    s[t] = v;
    __syncthreads();
    for (int off = 1; off < NB; off <<= 1) {
        int u = (t >= off) ? s[t - off] : 0;
        __syncthreads();
        s[t] += u;
        __syncthreads();
    }
    int base = s[t] - v;
    bbase[f * NB + t] = base;
    bcur [f * NB + t] = base;
}

// ---- partition: bucket-grouped (col|bf16val) + (row&255), chunked writes --
__global__ __launch_bounds__(256) void partition(const int* __restrict__ r0,
                                                 const int* __restrict__ c0,
                                                 const float* __restrict__ v0,
                                                 const int* __restrict__ r1,
                                                 const int* __restrict__ c1,
                                                 const float* __restrict__ v1,
                                                 int* __restrict__ bcur,
                                                 uint* __restrict__ cvy,
                                                 uchar* __restrict__ cvr, int E) {
    __shared__ int h[NB];
    __shared__ int cur[NB];
    const int f = blockIdx.y, t = threadIdx.x;
    const int*   rows = f ? r1 : r0;
    const int*   cols = f ? c1 : c0;
    const float* vals = f ? v1 : v0;
    const int base = blockIdx.x * EPB;

    h[t] = 0;
    __syncthreads();
    for (int k = 0; k < EPB / 256; ++k) {
        int e = base + k * 256 + t;
        if (e < E) atomicAdd(&h[rows[e] >> 8], 1);
    }
    __syncthreads();
    cur[t] = atomicAdd(&bcur[f * NB + t], h[t]);    // chunk base for bucket t
    __syncthreads();

    uint*  yout = cvy + (size_t)f * E;
    uchar* rout = cvr + (size_t)f * E;
    for (int k = 0; k < EPB / 256; ++k) {
        int e = base + k * 256 + t;
        if (e < E) {
            int r = rows[e];
            int pos = atomicAdd(&cur[r >> 8], 1);
            yout[pos] = ((uint)cols[e] << 16) | (uint)f2bf(vals[e]);
            rout[pos] = (uchar)(r & 255);
        }
    }
}

// ---- fused per-bucket LDS sort + gather: out[r] = relu(sum0 + sum1) ------
__device__ __forceinline__ void fma4(float4& a, float v, ushort4 h) {
    a.x = fmaf(v, bf2f(h.x), a.x);
    a.y = fmaf(v, bf2f(h.y), a.y);
    a.z = fmaf(v, bf2f(h.z), a.z);
    a.w = fmaf(v, bf2f(h.w), a.w);
}

__global__ __launch_bounds__(1024) void sort_gather(
        const uint* __restrict__ cvy, const uchar* __restrict__ cvr,
        const int* __restrict__ bbase, const int* __restrict__ bcur,
        const ushort* __restrict__ H, int BN,
        float* __restrict__ out, int E) {
    __shared__ uint cvl[2][CAP];          // 64 KB: sorted (col|val) per filter
    __shared__ int rp[2][NB + 1];         // per-local-row start into cvl
    __shared__ int hcnt[NB];
    __shared__ int curs[NB];
    __shared__ int sstart[2], scount[2], sovf[2];

    const int b = blockIdx.x;
    const int t = threadIdx.x;

    // ---- phase 1: sort this bucket's edges by row&255 into LDS ----
#pragma unroll 1
    for (int f = 0; f < 2; ++f) {
        if (t == 0) {
            int s0 = bbase[f * NB + b];
            int e0 = bcur [f * NB + b];
            sstart[f] = s0;
            scount[f] = e0 - s0;
            sovf[f]   = (e0 - s0) > CAP;
        }
        if (t < NB) hcnt[t] = 0;
        __syncthreads();
        const int s = sstart[f], n = scount[f];
        const uchar* rin = cvr + (size_t)f * E + s;
        const uint*  yin = cvy + (size_t)f * E + s;
        for (int i = t; i < n; i += 1024)
            atomicAdd(&hcnt[rin[i]], 1);
        __syncthreads();
        int v = (t < NB) ? hcnt[t] : 0;
        if (t < NB) curs[t] = v;
        __syncthreads();
        for (int off = 1; off < NB; off <<= 1) {    // inclusive Hillis-Steele
            int u = 0;
            if (t < NB && t >= off) u = curs[t - off];
            __syncthreads();
            if (t < NB) curs[t] += u;
            __syncthreads();
        }
        if (t < NB) {
            int ex = curs[t] - v;                   // exclusive base
            rp[f][t] = ex;
            curs[t] = ex;
        }
        if (t == 0) rp[f][NB] = n;
        __syncthreads();
        if (!sovf[f]) {
            for (int i = t; i < n; i += 1024) {
                uchar r = rin[i];
                int pos = atomicAdd(&curs[r], 1);
                cvl[f][pos] = __builtin_nontemporal_load(&yin[i]);
            }
        }
        __syncthreads();
    }

    // ---- phase 2: gather. 32 half-waves x 8 rows each ----
    const int half = t >> 5;              // 0..31
    const int sub  = t & 31;              // float4 column slot
    f32x4* outv = reinterpret_cast<f32x4*>(out);

#pragma unroll 1
    for (int k = 0; k < 8; ++k) {
        const int lr = k * 32 + half;                 // local row 0..255
        const long gr = (long)b * NB + lr;            // global row

        float4 a0 = make_float4(0.f, 0.f, 0.f, 0.f);
        float4 a1 = make_float4(0.f, 0.f, 0.f, 0.f);
        float4 a2 = make_float4(0.f, 0.f, 0.f, 0.f);
        float4 a3 = make_float4(0.f, 0.f, 0.f, 0.f);

#pragma unroll
        for (int f = 0; f < 2; ++f) {
            const ushort* Hf = H + (size_t)f * BN * 128;
            if (!sovf[f]) {
                int e = rp[f][lr];
                const int e1 = rp[f][lr + 1];
                for (; e + 7 < e1; e += 8) {
                    uint p0 = cvl[f][e],     p1 = cvl[f][e + 1];
                    uint p2 = cvl[f][e + 2], p3 = cvl[f][e + 3];
                    uint p4 = cvl[f][e + 4], p5 = cvl[f][e + 5];
                    uint p6 = cvl[f][e + 6], p7 = cvl[f][e + 7];
                    ushort4 h0 = reinterpret_cast<const ushort4*>(Hf + (size_t)(p0 >> 16) * 128)[sub];
                    ushort4 h1 = reinterpret_cast<const ushort4*>(Hf + (size_t)(p1 >> 16) * 128)[sub];
                    ushort4 h2 = reinterpret_cast<const ushort4*>(Hf + (size_t)(p2 >> 16) * 128)[sub];
                    ushort4 h3 = reinterpret_cast<const ushort4*>(Hf + (size_t)(p3 >> 16) * 128)[sub];
                    ushort4 h4 = reinterpret_cast<const ushort4*>(Hf + (size_t)(p4 >> 16) * 128)[sub];
                    ushort4 h5 = reinterpret_cast<const ushort4*>(Hf + (size_t)(p5 >> 16) * 128)[sub];
                    ushort4 h6 = reinterpret_cast<const ushort4*>(Hf + (size_t)(p6 >> 16) * 128)[sub];
                    ushort4 h7 = reinterpret_cast<const ushort4*>(Hf + (size_t)(p7 >> 16) * 128)[sub];
                    fma4(a0, __uint_as_float(p0 << 16), h0);
                    fma4(a1, __uint_as_float(p1 << 16), h1);
                    fma4(a2, __uint_as_float(p2 << 16), h2);
                    fma4(a3, __uint_as_float(p3 << 16), h3);
                    fma4(a0, __uint_as_float(p4 << 16), h4);
                    fma4(a1, __uint_as_float(p5 << 16), h5);
                    fma4(a2, __uint_as_float(p6 << 16), h6);
                    fma4(a3, __uint_as_float(p7 << 16), h7);
                }
                for (; e + 3 < e1; e += 4) {
                    uint p0 = cvl[f][e],     p1 = cvl[f][e + 1];
                    uint p2 = cvl[f][e + 2], p3 = cvl[f][e + 3];
                    ushort4 h0 = reinterpret_cast<const ushort4*>(Hf + (size_t)(p0 >> 16) * 128)[sub];
                    ushort4 h1 = reinterpret_cast<const ushort4*>(Hf + (size_t)(p1 >> 16) * 128)[sub];
                    ushort4 h2 = reinterpret_cast<const ushort4*>(Hf + (size_t)(p2 >> 16) * 128)[sub];
                    ushort4 h3 = reinterpret_cast<const ushort4*>(Hf + (size_t)(p3 >> 16) * 128)[sub];
                    fma4(a0, __uint_as_float(p0 << 16), h0);
                    fma4(a1, __uint_as_float(p1 << 16), h1);
                    fma4(a2, __uint_as_float(p2 << 16), h2);
                    fma4(a3, __uint_as_float(p3 << 16), h3);
                }
                for (; e < e1; ++e) {
                    uint p0 = cvl[f][e];
                    ushort4 h0 = reinterpret_cast<const ushort4*>(Hf + (size_t)(p0 >> 16) * 128)[sub];
                    fma4(a0, __uint_as_float(p0 << 16), h0);
                }
            } else {
                // never-taken safety path (bucket > CAP): scan whole bucket
                const int s = sstart[f], n = scount[f];
                const uchar* rin = cvr + (size_t)f * E + s;
                const uint*  yin = cvy + (size_t)f * E + s;
                for (int i = 0; i < n; ++i) {
                    if (rin[i] == (uchar)lr) {
                        uint p0 = yin[i];
                        ushort4 h0 = reinterpret_cast<const ushort4*>(Hf + (size_t)(p0 >> 16) * 128)[sub];
                        fma4(a0, __uint_as_float(p0 << 16), h0);
                    }
                }
            }
        }

        f32x4 o;
        o.x = fmaxf((a0.x + a1.x) + (a2.x + a3.x), 0.0f);
        o.y = fmaxf((a0.y + a1.y) + (a2.y + a3.y), 0.0f);
        o.z = fmaxf((a0.z + a1.z) + (a2.z + a3.z), 0.0f);
        o.w = fmaxf((a0.w + a1.w) + (a2.w + a3.w), 0.0f);
        __builtin_nontemporal_store(o, outv + gr * 32 + sub);
    }
}

extern "C" void kernel_launch(void* const* d_in, const int* in_sizes, int n_in,
                              void* d_out, int out_size, void* d_ws, size_t ws_size,
                              hipStream_t stream) {
    const float* X     = (const float*)d_in[0];
    const float* W0    = (const float*)d_in[1];
    const float* W1    = (const float*)d_in[2];
    const int*   rows0 = (const int*)d_in[3];
    const int*   cols0 = (const int*)d_in[4];
    const float* vals0 = (const float*)d_in[5];
    const int*   rows1 = (const int*)d_in[6];
    const int*   cols1 = (const int*)d_in[7];
    const float* vals1 = (const float*)d_in[8];
    float* out = (float*)d_out;

    const int BN = in_sizes[0] / 128;               // 65536
    const int E  = in_sizes[3];                     // 1048576
    const int partb = (E + EPB - 1) / EPB;          // 128

    // Workspace (~42.2 MB; harness provides >= 54.7 MB, proven in round 8):
    char* ws = (char*)d_ws;
    size_t off = 0;
    auto alloc = [&](size_t bytes) {
        void* p = ws + off;
        off = (off + bytes + 255) & ~(size_t)255;
        return p;
    };
    ushort* H     = (ushort*)alloc((size_t)2 * BN * 128 * sizeof(ushort)); // 32 MiB
    uint4*  Wswz  = (uint4*) alloc((size_t)2 * 128 * 128 * sizeof(ushort)); // 128 KiB
    uint*   cvy   = (uint*)  alloc((size_t)2 * E * sizeof(uint));           // 8 MiB
    uchar*  cvr   = (uchar*) alloc((size_t)2 * E * sizeof(uchar));          // 2 MiB
    int*    cnt   = (int*)   alloc((size_t)2 * NB * sizeof(int));
    int*    bbase = (int*)   alloc((size_t)2 * NB * sizeof(int));
    int*    bcur  = (int*)   alloc((size_t)2 * NB * sizeof(int));

    w_swz<<<64, 64, 0, stream>>>(W0, W1, Wswz);
    gemm_mfma<<<BN / 64, 256, 0, stream>>>(X, (const i32x4*)Wswz, H, BN);

    hipMemsetAsync(cnt, 0, (size_t)2 * NB * sizeof(int), stream);
    hist_coarse<<<dim3(partb, 2), 256, 0, stream>>>(rows0, rows1, cnt, E);
    scan_coarse<<<2, 256, 0, stream>>>(cnt, bbase, bcur);
    partition<<<dim3(partb, 2), 256, 0, stream>>>(rows0, cols0, vals0,
                                                  rows1, cols1, vals1,
                                                  bcur, cvy, cvr, E);
    sort_gather<<<NB, 1024, 0, stream>>>(cvy, cvr, bbase, bcur, H, BN, out, E);
}